// Round 9
// baseline (100.613 us; speedup 1.0000x reference)
//
#include <hip/hip_runtime.h>

typedef _Float16 f16x4 __attribute__((ext_vector_type(4)));
typedef _Float16 f16x8 __attribute__((ext_vector_type(8)));
typedef unsigned short u16x8 __attribute__((ext_vector_type(8)));
typedef float f32x4 __attribute__((ext_vector_type(4)));

#define NS 1024
#define NQ 1024
#define DD 128
#define NWAY 8
#define SCHUNK 128
#define QPER 16
#define NBLK 512   // main grid: 8 sblk x 64 qblk = exactly 2 blocks/CU

// d_ws layout (bytes):
//   0        part  [8][NQ][NWAY] f32   (256 KB)
//   0x40000  counter (unsigned, zeroed by prep)
//   0x40100  sup16 [NS][DD] f16        (256 KB)
//   0x80100  q16   [NQ][DD] f16        (256 KB)
//   0xC0100  w1f   [16 frag][64 lane][8] f16  (16 KB, fragment-ordered)

// Prep: one-time f32->f16 conversion of support/query/W1 (W1 directly in
// MFMA fragment order) + zero the completion counter. Keeping conversions
// out of the main kernel removes the float4/cvt peak register pressure
// that drove every spill (R3/R5/R7).
__global__ void siamese_prep(const float* __restrict__ sx,
                             const float* __restrict__ qx,
                             const float* __restrict__ W1,
                             _Float16* __restrict__ sup16,
                             _Float16* __restrict__ q16,
                             _Float16* __restrict__ w1f,
                             unsigned* __restrict__ counter)
{
    if (blockIdx.x == 0 && threadIdx.x == 0) *counter = 0u;
    const int tid = blockIdx.x * 256 + threadIdx.x;
    if (blockIdx.x < 128) {                       // support: 32768 float4
        float4 v = ((const float4*)sx)[tid];
        f16x4 h; h[0] = (_Float16)v.x; h[1] = (_Float16)v.y;
        h[2] = (_Float16)v.z; h[3] = (_Float16)v.w;
        ((f16x4*)sup16)[tid] = h;
    } else if (blockIdx.x < 256) {                // query: 32768 float4
        const int i = tid - 32768;
        float4 v = ((const float4*)qx)[i];
        f16x4 h; h[0] = (_Float16)v.x; h[1] = (_Float16)v.y;
        h[2] = (_Float16)v.z; h[3] = (_Float16)v.w;
        ((f16x4*)q16)[i] = h;
    } else {                                      // W1 frags: 16*64 = 1024
        const int i = tid - 65536;
        const int jk = i >> 6, l = i & 63;
        const int h = (jk >> 2) * 16 + (l & 15);
        const int d = (jk & 3) * 32 + (l >> 4) * 8;
        const float* wp = W1 + h * DD + d;
        float4 v0 = *(const float4*)(wp);
        float4 v1 = *(const float4*)(wp + 4);
        f16x8 s;
        s[0] = (_Float16)v0.x; s[1] = (_Float16)v0.y;
        s[2] = (_Float16)v0.z; s[3] = (_Float16)v0.w;
        s[4] = (_Float16)v1.x; s[5] = (_Float16)v1.y;
        s[6] = (_Float16)v1.z; s[7] = (_Float16)v1.w;
        *(f16x8*)(w1f + (size_t)i * 8) = s;
    }
}

// Fused main: 128 supports x 16 queries per block, grid 512 = exactly 2
// blocks/CU at (256,2) -> one co-resident round. The last block to finish
// (device counter) performs count/mean/log_softmax in-block — no separate
// finalize dispatch.
// sim(q,s) = relu(|q-s| @ W1^T + b1) @ W2; b2 dropped (log_softmax shift-
// invariant). MFMA: A = W1 fragment, B = diff fragment -> C rows are h,
// cols are s, so the h-reduction is per-lane fma + 2 cross-quad shuffles.
// launch_bounds MUST stay (256,2): caps of 170/128 regs (R3/R5/R7) all
// produced 8-100 MB of scratch spill traffic. (256,2) is spill-free.
__global__ __launch_bounds__(256, 2) void siamese_main(
    const _Float16* __restrict__ sup16,
    const int* __restrict__ support_y,
    const _Float16* __restrict__ q16,
    const _Float16* __restrict__ w1f,
    const float* __restrict__ b1,
    const float* __restrict__ W2,
    float* __restrict__ part,      // [8 sblk][NQ][NWAY]
    unsigned* __restrict__ counter,
    float* __restrict__ out)       // [NQ][NWAY]
{
    __shared__ _Float16 qtile[QPER][DD];       // 4 KB
    __shared__ float clsbuf[QPER][NWAY];       // 512 B
    __shared__ unsigned lastflag;
    __shared__ float cnt8[NWAY];

    const int t = threadIdx.x;
    const int wave = t >> 6;
    const int lane = t & 63;
    const int c = lane & 15;     // MFMA n index -> support col
    const int quad = lane >> 4;  // MFMA k-group / C row-group

    const int sblk = blockIdx.x & 7;
    const int qblk = blockIdx.x >> 3;
    const int s0 = sblk * SCHUNK;
    const int q0 = qblk * QPER;

    // ---- one-time: support B-fragments (pure f16 16B loads) ----
    f16x8 sup[2][4];
#pragma unroll
    for (int ii = 0; ii < 2; ++ii) {
        const _Float16* sp = sup16 + (size_t)(s0 + (2 * wave + ii) * 16 + c) * DD + quad * 8;
#pragma unroll
        for (int k = 0; k < 4; ++k)
            sup[ii][k] = *(const f16x8*)(sp + k * 32);
    }

    // ---- one-time: W1 A-fragments (fragment-ordered, 16B loads) ----
    f16x8 afrag[4][4];
#pragma unroll
    for (int j = 0; j < 4; ++j)
#pragma unroll
        for (int k = 0; k < 4; ++k)
            afrag[j][k] = *(const f16x8*)(w1f + (size_t)((j * 4 + k) * 64 + lane) * 8);

    // ---- one-time: b1/W2 rows for this lane (h = j*16 + quad*4 + r) ----
    f32x4 b1v[4], w2v[4];
#pragma unroll
    for (int j = 0; j < 4; ++j) {
        b1v[j] = *(const f32x4*)(b1 + j * 16 + quad * 4);
        w2v[j] = *(const f32x4*)(W2 + j * 16 + quad * 4);
    }

    int lbl[2];
#pragma unroll
    for (int ii = 0; ii < 2; ++ii)
        lbl[ii] = support_y[s0 + (2 * wave + ii) * 16 + c];

    // ---- stage QPER query rows (f16, direct 16B copies) ----
    {
        const int q = t >> 4;
        const int dd = (t & 15) * 8;
        *(f16x8*)&qtile[q][dd] = *(const f16x8*)(q16 + (size_t)(q0 + q) * DD + dd);
    }
    if (t < QPER * NWAY) clsbuf[t >> 3][t & 7] = 0.f;
    __syncthreads();

    // software-pipelined q-loop: qf for q+1 prefetched before q's epilogue
    f16x8 qf[4];
#pragma unroll
    for (int k = 0; k < 4; ++k)
        qf[k] = *(const f16x8*)&qtile[0][k * 32 + quad * 8];

    for (int qq = 0; qq < QPER; ++qq) {
        f32x4 acc[2][4];
#pragma unroll
        for (int ii = 0; ii < 2; ++ii)
#pragma unroll
            for (int j = 0; j < 4; ++j)
                acc[ii][j] = b1v[j];

#pragma unroll
        for (int k = 0; k < 4; ++k) {
#pragma unroll
            for (int ii = 0; ii < 2; ++ii) {
                union { f16x8 f; u16x8 u; } cv;
                cv.f = sup[ii][k] - qf[k];
                cv.u = cv.u & (unsigned short)0x7fffu;  // |diff|
#pragma unroll
                for (int j = 0; j < 4; ++j)
                    acc[ii][j] = __builtin_amdgcn_mfma_f32_16x16x32_f16(
                        afrag[j][k], cv.f, acc[ii][j], 0, 0, 0);
            }
        }

        // prefetch next query's fragments (hides ds_read latency behind
        // the epilogue and the MFMA-result latency behind these reads)
        f16x8 qn[4];
        const int nq = (qq + 1) & (QPER - 1);
#pragma unroll
        for (int k = 0; k < 4; ++k)
            qn[k] = *(const f16x8*)&qtile[nq][k * 32 + quad * 8];

        // epilogue: per-lane fma over own 16 h values, then cross-quad sum
#pragma unroll
        for (int ii = 0; ii < 2; ++ii) {
            float val = 0.f;
#pragma unroll
            for (int j = 0; j < 4; ++j)
#pragma unroll
                for (int r = 0; r < 4; ++r)
                    val = fmaf(fmaxf(acc[ii][j][r], 0.f), w2v[j][r], val);
            val += __shfl_xor(val, 16);
            val += __shfl_xor(val, 32);
            if (quad == 0) atomicAdd(&clsbuf[qq][lbl[ii]], val);
        }

#pragma unroll
        for (int k = 0; k < 4; ++k) qf[k] = qn[k];
    }
    __syncthreads();

    // one coalesced 128-float store: part[sblk][q0..q0+15][0..7]
    if (t < QPER * NWAY)
        part[(size_t)sblk * (NQ * NWAY) + q0 * NWAY + t] = clsbuf[t >> 3][t & 7];
    __syncthreads();   // drains the part stores (vmcnt 0 before barrier)

    if (t == 0) {
        __threadfence();                               // release: parts visible
        unsigned prev = atomicAdd(counter, 1u);
        lastflag = (prev == (unsigned)(NBLK - 1));
    }
    __syncthreads();
    if (!lastflag) return;

    // ================= last-block finalize =================
    __threadfence();   // acquire: invalidate stale cache lines

    if (t < NWAY) cnt8[t] = 0.f;
    __syncthreads();
#pragma unroll
    for (int i = 0; i < 4; ++i)
        atomicAdd(&cnt8[support_y[t * 4 + i]], 1.0f);
    __syncthreads();

    const f32x4 clo = *(const f32x4*)&cnt8[0];
    const f32x4 chi = *(const f32x4*)&cnt8[4];

#pragma unroll
    for (int rep = 0; rep < 4; ++rep) {
        const int q = rep * 256 + t;
        f32x4 slo = (f32x4){0.f, 0.f, 0.f, 0.f};
        f32x4 shi = (f32x4){0.f, 0.f, 0.f, 0.f};
#pragma unroll
        for (int sb = 0; sb < 8; ++sb) {
            const float* p = part + ((size_t)sb * NQ + q) * NWAY;
            slo += *(const f32x4*)(p);
            shi += *(const f32x4*)(p + 4);
        }
        f32x4 lo = slo / clo;
        f32x4 hi = shi / chi;
        float mx = fmaxf(fmaxf(fmaxf(lo[0], lo[1]), fmaxf(lo[2], lo[3])),
                         fmaxf(fmaxf(hi[0], hi[1]), fmaxf(hi[2], hi[3])));
        float ss = 0.f;
#pragma unroll
        for (int k = 0; k < 4; ++k) ss += expf(lo[k] - mx);
#pragma unroll
        for (int k = 0; k < 4; ++k) ss += expf(hi[k] - mx);
        const float lse = mx + logf(ss);
#pragma unroll
        for (int k = 0; k < 4; ++k) lo[k] -= lse;
#pragma unroll
        for (int k = 0; k < 4; ++k) hi[k] -= lse;
        *(f32x4*)(out + (size_t)q * NWAY) = lo;
        *(f32x4*)(out + (size_t)q * NWAY + 4) = hi;
    }
}

extern "C" void kernel_launch(void* const* d_in, const int* in_sizes, int n_in,
                              void* d_out, int out_size, void* d_ws, size_t ws_size,
                              hipStream_t stream) {
    const float* support_x = (const float*)d_in[0];
    const int* support_y   = (const int*)d_in[1];
    const float* query_x   = (const float*)d_in[2];
    // d_in[3] = n_way (scalar, fixed at 8) — unused
    const float* W1 = (const float*)d_in[4];
    const float* b1 = (const float*)d_in[5];
    const float* W2 = (const float*)d_in[6];
    // d_in[7] = b2 — dropped (uniform logit shift, log_softmax-invariant)

    char* ws = (char*)d_ws;
    float* part       = (float*)(ws);                 // 256 KB
    unsigned* counter = (unsigned*)(ws + 0x40000);    // 4 B (zeroed by prep)
    _Float16* sup16   = (_Float16*)(ws + 0x40100);    // 256 KB
    _Float16* q16     = (_Float16*)(ws + 0x80100);    // 256 KB
    _Float16* w1f     = (_Float16*)(ws + 0xC0100);    // 16 KB

    siamese_prep<<<dim3(260), dim3(256), 0, stream>>>(
        support_x, query_x, W1, sup16, q16, w1f, counter);
    siamese_main<<<dim3(NBLK), dim3(256), 0, stream>>>(
        sup16, support_y, q16, w1f, b1, W2, part, counter, (float*)d_out);
}

// Round 10
// 92.576 us; speedup vs baseline: 1.0868x; 1.0868x over previous
//
#include <hip/hip_runtime.h>

typedef _Float16 f16x4 __attribute__((ext_vector_type(4)));
typedef _Float16 f16x8 __attribute__((ext_vector_type(8)));
typedef unsigned short u16x8 __attribute__((ext_vector_type(8)));
typedef float f32x4 __attribute__((ext_vector_type(4)));

#define NS 1024
#define NQ 1024
#define DD 128
#define NWAY 8
#define SCHUNK 64            // supports per block (4 waves x 16)
#define NSBLK (NS / SCHUNK)  // 16
#define QPER 16              // queries per block

// d_ws layout (bytes):
//   0         part  [NSBLK][NQ][NWAY] f32  (512 KB)
//   0x80000   sup16 [NS][DD] f16           (256 KB)
//   0xC0000   q16   [NQ][DD] f16           (256 KB)
//   0x100000  w1f   [16 frag][64 lane][8] f16 (16 KB, fragment-ordered)

// Prep: one-time f32->f16 conversion of support/query/W1 (W1 directly in
// MFMA fragment order). Keeping conversions out of the main kernel removes
// the float4/cvt peak register pressure that drove every spill (R3/R5/R7).
__global__ void siamese_prep(const float* __restrict__ sx,
                             const float* __restrict__ qx,
                             const float* __restrict__ W1,
                             _Float16* __restrict__ sup16,
                             _Float16* __restrict__ q16,
                             _Float16* __restrict__ w1f)
{
    const int tid = blockIdx.x * 256 + threadIdx.x;
    if (blockIdx.x < 128) {                       // support: 32768 float4
        float4 v = ((const float4*)sx)[tid];
        f16x4 h; h[0] = (_Float16)v.x; h[1] = (_Float16)v.y;
        h[2] = (_Float16)v.z; h[3] = (_Float16)v.w;
        ((f16x4*)sup16)[tid] = h;
    } else if (blockIdx.x < 256) {                // query: 32768 float4
        const int i = tid - 32768;
        float4 v = ((const float4*)qx)[i];
        f16x4 h; h[0] = (_Float16)v.x; h[1] = (_Float16)v.y;
        h[2] = (_Float16)v.z; h[3] = (_Float16)v.w;
        ((f16x4*)q16)[i] = h;
    } else {                                      // W1 frags: 16*64 = 1024
        const int i = tid - 65536;
        const int jk = i >> 6, l = i & 63;
        const int h = (jk >> 2) * 16 + (l & 15);
        const int d = (jk & 3) * 32 + (l >> 4) * 8;
        const float* wp = W1 + h * DD + d;
        float4 v0 = *(const float4*)(wp);
        float4 v1 = *(const float4*)(wp + 4);
        f16x8 s;
        s[0] = (_Float16)v0.x; s[1] = (_Float16)v0.y;
        s[2] = (_Float16)v0.z; s[3] = (_Float16)v0.w;
        s[4] = (_Float16)v1.x; s[5] = (_Float16)v1.y;
        s[6] = (_Float16)v1.z; s[7] = (_Float16)v1.w;
        *(f16x8*)(w1f + (size_t)i * 8) = s;
    }
}

// Main: 64 supports x 16 queries per block (wave owns 16 supports x 64 h),
// grid 1024. sim(q,s) = relu(|q-s| @ W1^T + b1) @ W2, class-bucketed via
// LDS atomics; b2 dropped (log_softmax shift-invariant).
// MFMA: A = W1 fragment, B = diff fragment -> C rows are h, cols are s;
// h-reduction = per-lane fma + 2 cross-quad shuffles.
// MODULO-2 SOFTWARE PIPELINE: MFMAs for query q+1 issue interleaved with
// the epilogue VALU chain of query q (independent), hiding the serial
// MFMA-latency -> epilogue -> shuffle chain that kept R4-R8 at ~65% stall.
// launch_bounds MUST stay (256,2): tighter caps (R3/R5/R7) all produced
// 8-100 MB of scratch spill traffic. Live regs here ~190 < 256.
__global__ __launch_bounds__(256, 2) void siamese_main(
    const _Float16* __restrict__ sup16,
    const int* __restrict__ support_y,
    const _Float16* __restrict__ q16,
    const _Float16* __restrict__ w1f,
    const float* __restrict__ b1,
    const float* __restrict__ W2,
    float* __restrict__ part)   // [NSBLK][NQ][NWAY]
{
    __shared__ _Float16 qtile[QPER][DD];       // 4 KB
    __shared__ float clsbuf[QPER][NWAY];       // 512 B

    const int t = threadIdx.x;
    const int wave = t >> 6;
    const int lane = t & 63;
    const int c = lane & 15;     // MFMA n index -> support col
    const int quad = lane >> 4;  // MFMA k-group / C row-group

    const int sblk = blockIdx.x & (NSBLK - 1);
    const int qblk = blockIdx.x >> 4;
    const int s0 = sblk * SCHUNK;
    const int q0 = qblk * QPER;

    // ---- one-time: support B-fragments (pure f16 16B loads) ----
    // sup[k]: lane (quad,c) holds sup16[s0+wave*16+c][k*32+quad*8 ..+8)
    f16x8 sup[4];
    {
        const _Float16* sp = sup16 + (size_t)(s0 + wave * 16 + c) * DD + quad * 8;
#pragma unroll
        for (int k = 0; k < 4; ++k)
            sup[k] = *(const f16x8*)(sp + k * 32);
    }

    // ---- one-time: W1 A-fragments (fragment-ordered, 16B loads) ----
    f16x8 afrag[4][4];
#pragma unroll
    for (int j = 0; j < 4; ++j)
#pragma unroll
        for (int k = 0; k < 4; ++k)
            afrag[j][k] = *(const f16x8*)(w1f + (size_t)((j * 4 + k) * 64 + lane) * 8);

    // ---- one-time: b1/W2 rows for this lane (h = j*16 + quad*4 + r) ----
    f32x4 b1v[4], w2v[4];
#pragma unroll
    for (int j = 0; j < 4; ++j) {
        b1v[j] = *(const f32x4*)(b1 + j * 16 + quad * 4);
        w2v[j] = *(const f32x4*)(W2 + j * 16 + quad * 4);
    }

    const int lbl = support_y[s0 + wave * 16 + c];

    // ---- stage QPER query rows (f16, direct 16B copies) ----
    {
        const int q = t >> 4;
        const int dd = (t & 15) * 8;
        *(f16x8*)&qtile[q][dd] = *(const f16x8*)(q16 + (size_t)(q0 + q) * DD + dd);
    }
    if (t < QPER * NWAY) clsbuf[t >> 3][t & 7] = 0.f;
    __syncthreads();

    auto read_qf = [&](f16x8 (&qf)[4], int qq) {
#pragma unroll
        for (int k = 0; k < 4; ++k)
            qf[k] = *(const f16x8*)&qtile[qq][k * 32 + quad * 8];
    };
    auto mfma_q = [&](f32x4 (&acc)[4], const f16x8 (&qf)[4]) {
#pragma unroll
        for (int j = 0; j < 4; ++j) acc[j] = b1v[j];
#pragma unroll
        for (int k = 0; k < 4; ++k) {
            union { f16x8 f; u16x8 u; } cv;
            cv.f = sup[k] - qf[k];
            cv.u = cv.u & (unsigned short)0x7fffu;  // |diff|
#pragma unroll
            for (int j = 0; j < 4; ++j)
                acc[j] = __builtin_amdgcn_mfma_f32_16x16x32_f16(
                    afrag[j][k], cv.f, acc[j], 0, 0, 0);
        }
    };
    auto epi = [&](const f32x4 (&acc)[4], int qq) {
        float val = 0.f;
#pragma unroll
        for (int j = 0; j < 4; ++j)
#pragma unroll
            for (int r = 0; r < 4; ++r)
                val = fmaf(fmaxf(acc[j][r], 0.f), w2v[j][r], val);
        val += __shfl_xor(val, 16);
        val += __shfl_xor(val, 32);
        if (quad == 0) atomicAdd(&clsbuf[qq][lbl], val);
    };

    // -------- modulo-2 skewed pipeline over the 16 queries --------
    f16x8 qfA[4], qfB[4];
    f32x4 accA[4], accB[4];
    read_qf(qfA, 0);
    mfma_q(accA, qfA);
    read_qf(qfB, 1);
    for (int qq = 0; qq + 2 < QPER; qq += 2) {
        mfma_q(accB, qfB);      // MFMAs for qq+1 ...
        epi(accA, qq);          // ... interleave with epilogue of qq
        read_qf(qfA, qq + 2);
        mfma_q(accA, qfA);      // MFMAs for qq+2 ...
        epi(accB, qq + 1);      // ... interleave with epilogue of qq+1
        read_qf(qfB, qq + 3);
    }
    mfma_q(accB, qfB);
    epi(accA, QPER - 2);
    epi(accB, QPER - 1);

    __syncthreads();

    // one coalesced 128-float store: part[sblk][q0..q0+15][0..7]
    if (t < QPER * NWAY)
        part[(size_t)sblk * (NQ * NWAY) + q0 * NWAY + t] = clsbuf[t >> 3][t & 7];
}

// Finalize: sum NSBLK partials, counts, per-class mean, log_softmax.
// Grid 8 x 128 threads (one thread per query).
__global__ void siamese_finalize(
    const int* __restrict__ support_y,
    const float* __restrict__ part,
    float* __restrict__ out)
{
    __shared__ float cnt[NWAY];
    const int t = threadIdx.x;
    if (t < NWAY) cnt[t] = 0.f;
    __syncthreads();
#pragma unroll
    for (int i = 0; i < NS / 128; ++i)
        atomicAdd(&cnt[support_y[t * (NS / 128) + i]], 1.0f);
    __syncthreads();

    const int q = blockIdx.x * 128 + t;
    float lg[NWAY];
    float mx = -1e30f;
#pragma unroll
    for (int k = 0; k < NWAY; ++k) {
        float s = 0.f;
#pragma unroll
        for (int sb = 0; sb < NSBLK; ++sb)
            s += part[(size_t)sb * (NQ * NWAY) + q * NWAY + k];
        lg[k] = s / cnt[k];
        mx = fmaxf(mx, lg[k]);
    }
    float ss = 0.f;
#pragma unroll
    for (int k = 0; k < NWAY; ++k) ss += expf(lg[k] - mx);
    const float lse = mx + logf(ss);
#pragma unroll
    for (int k = 0; k < NWAY; ++k) out[q * NWAY + k] = lg[k] - lse;
}

extern "C" void kernel_launch(void* const* d_in, const int* in_sizes, int n_in,
                              void* d_out, int out_size, void* d_ws, size_t ws_size,
                              hipStream_t stream) {
    const float* support_x = (const float*)d_in[0];
    const int* support_y   = (const int*)d_in[1];
    const float* query_x   = (const float*)d_in[2];
    // d_in[3] = n_way (scalar, fixed at 8) — unused
    const float* W1 = (const float*)d_in[4];
    const float* b1 = (const float*)d_in[5];
    const float* W2 = (const float*)d_in[6];
    // d_in[7] = b2 — dropped (uniform logit shift, log_softmax-invariant)

    char* ws = (char*)d_ws;
    float* part       = (float*)(ws);                  // 512 KB
    _Float16* sup16   = (_Float16*)(ws + 0x80000);     // 256 KB
    _Float16* q16     = (_Float16*)(ws + 0xC0000);     // 256 KB
    _Float16* w1f     = (_Float16*)(ws + 0x100000);    // 16 KB

    siamese_prep<<<dim3(260), dim3(256), 0, stream>>>(
        support_x, query_x, W1, sup16, q16, w1f);
    siamese_main<<<dim3(NSBLK * (NQ / QPER)), dim3(256), 0, stream>>>(
        sup16, support_y, q16, w1f, b1, W2, part);
    siamese_finalize<<<dim3(NQ / 128), dim3(128), 0, stream>>>(
        support_y, part, (float*)d_out);
}